// Round 5
// baseline (43.633 us; speedup 1.0000x reference)
//
#include <hip/hip_runtime.h>
#include <cfloat>
#include <cstdint>

#define BB    4              // batches
#define NN    8192           // points per cloud
#define NT    8              // rows (gt queries) per thread
#define TPB   256            // threads per block
#define NTILE (NT*TPB)       // 2048 rows per block
#define NBQ   (NN/NTILE)     // 4 row-tiles
#define MSL   64             // pred points (cols) per block
#define MS    (NN/MSL)       // 128 col slices
#define NPAIR (MSL/2)        // 32 col-pairs
#define NHW   (TPB/32)       // 8 half-waves per block

// raw v_min3/v_min: bypass LLVM's fmin canonicalization (inputs are finite)
static __device__ __forceinline__ float vmin3(float a, float b, float c) {
    float r;
    asm("v_min3_f32 %0, %1, %2, %3" : "=v"(r) : "v"(a), "v"(b), "v"(c));
    return r;
}
static __device__ __forceinline__ float vmin2(float a, float b) {
    float r;
    asm("v_min_f32 %0, %1, %2" : "=v"(r) : "v"(a), "v"(b));
    return r;
}

// order-preserving float<->uint mapping (finite floats)
__device__ __forceinline__ unsigned mapf(float f) {
    unsigned b = __float_as_uint(f);
    return b ^ ((unsigned)((int)b >> 31) | 0x80000000u);
}
__device__ __forceinline__ float unmapf(unsigned u) {
    unsigned b = u ^ (((u & 0x80000000u) != 0u) ? 0x80000000u : 0xFFFFFFFFu);
    return __uint_as_float(b);
}

// One pass over the distance matrix: rows = gt cloud (dist1), cols = pred
// cloud (dist2). Block: 2048 rows (regs) x 64 cols (LDS). sqn folded into the
// innermost FMA addend so d already = true squared distance; row-min in regs,
// col-min in per-half-wave LDS arrays with lane-staggered race-free RMW.
__global__ __launch_bounds__(TPB) void chamfer_onepass_kernel(
    const float* __restrict__ pred, const float* __restrict__ gt,
    const float* __restrict__ coords, unsigned* __restrict__ ws)
{
    const int b  = blockIdx.y;
    const int nb = blockIdx.x & (NBQ - 1);
    const int ms = blockIdx.x >> 2;          // blockIdx.x / NBQ
    const size_t base = (size_t)b * 3 * NN;
    const float* gr = gt     + base;
    const float* pr = pred   + base;
    const float* cc = coords + base;

    __shared__ float4 tileE[NPAIR];          // pred point 2j   : (-2x,-2y,-2z,|q|^2)
    __shared__ float4 tileO[NPAIR];          // pred point 2j+1
    __shared__ float  colmin[NHW][MSL];      // per-half-wave col partial mins

    const int tid = threadIdx.x;

    // stage pred slice
    if (tid < MSL) {
        int m   = ms * MSL + tid;
        float x = cc[m]        + pr[m];
        float y = cc[NN + m]   + pr[NN + m];
        float z = cc[2*NN + m] + pr[2*NN + m];
        float4 v = make_float4(-2.f*x, -2.f*y, -2.f*z, fmaf(x, x, fmaf(y, y, z*z)));
        if (tid & 1) tileO[tid >> 1] = v; else tileE[tid >> 1] = v;
    }
    #pragma unroll
    for (int j = tid; j < NHW * MSL; j += TPB) (&colmin[0][0])[j] = FLT_MAX;

    // gt rows in registers
    float px[NT], py[NT], pz[NT], sqn[NT], mv[NT];
    const int n0 = nb * NTILE + tid;
    #pragma unroll
    for (int k = 0; k < NT; ++k) {
        int n   = n0 + k * TPB;
        float x = cc[n]        + gr[n];
        float y = cc[NN + n]   + gr[NN + n];
        float z = cc[2*NN + n] + gr[2*NN + n];
        px[k] = x; py[k] = y; pz[k] = z;
        sqn[k] = fmaf(x, x, fmaf(y, y, z*z));
        mv[k]  = FLT_MAX;
    }
    __syncthreads();

    const int ll = tid & 31;                 // lane within half-wave
    float* cm = colmin[tid >> 5];

    int jp = ll;
    float4 a = tileE[jp];
    float4 c = tileO[jp];
    #pragma unroll 2
    for (int i = 0; i < NPAIR; ++i) {
        const int jn = (jp + 1) & (NPAIR - 1);
        float4 an = tileE[jn];               // prefetch next pair
        float4 cn = tileO[jn];
        float d0[NT], d1[NT];
        #pragma unroll
        for (int k = 0; k < NT; ++k) {
            float w0 = a.w + sqn[k];         // fold |p|^2 into the FMA addend
            float w1 = c.w + sqn[k];
            d0[k] = fmaf(px[k], a.x, fmaf(py[k], a.y, fmaf(pz[k], a.z, w0)));
            d1[k] = fmaf(px[k], c.x, fmaf(py[k], c.y, fmaf(pz[k], c.z, w1)));
            mv[k] = vmin3(mv[k], d0[k], d1[k]);
        }
        // col partial: 8 -> 1 via 3x min3 + 1x min
        float t0 = vmin3(d0[0], d0[1], d0[2]);
        float u0 = vmin3(d0[3], d0[4], d0[5]);
        float s0 = vmin3(d0[6], d0[7], t0);
        float c0 = vmin2(s0, u0);
        float t1 = vmin3(d1[0], d1[1], d1[2]);
        float u1 = vmin3(d1[3], d1[4], d1[5]);
        float s1 = vmin3(d1[6], d1[7], t1);
        float c1 = vmin2(s1, u1);
        // half-wave colmin RMW: distinct float2 slot per lane each step
        float2* slot = (float2*)&cm[2 * jp];
        float2 old = *slot;
        old.x = vmin2(old.x, c0);
        old.y = vmin2(old.y, c1);
        *slot = old;
        jp = jn; a = an; c = cn;
    }

    // dist1: row mins -> global (mv already includes sqn)
    unsigned* wsrow = ws + (size_t)b * NN;
    #pragma unroll
    for (int k = 0; k < NT; ++k)
        atomicMin(&wsrow[n0 + k * TPB], mapf(mv[k]));

    __syncthreads();
    // dist2: combine 8 half-wave arrays, one atomic per col
    unsigned* wscol = ws + (size_t)BB * NN + (size_t)b * NN;
    if (tid < MSL) {
        float v = vmin3(colmin[0][tid], colmin[1][tid], colmin[2][tid]);
        v = vmin3(v, colmin[3][tid], colmin[4][tid]);
        v = vmin3(v, colmin[5][tid], colmin[6][tid]);
        v = vmin2(v, colmin[7][tid]);
        atomicMin(&wscol[ms * MSL + tid], mapf(v));
    }
}

// init mins to +inf in mapped-uint space (0xFFFFFFFF), 16384 uint4 stores
__global__ __launch_bounds__(256) void ws_init_kernel(unsigned* __restrict__ ws)
{
    ((uint4*)ws)[blockIdx.x * 256 + threadIdx.x] = make_uint4(~0u, ~0u, ~0u, ~0u);
}

// stage A: 64 blocks x 256 threads, uint4 per thread -> 64 partials
__global__ __launch_bounds__(256) void chamfer_reduce_a(
    const unsigned* __restrict__ ws, float* __restrict__ partial)
{
    int idx = blockIdx.x * 256 + threadIdx.x;
    const uint4* p = (const uint4*)ws;
    uint4 u = p[idx];
    float s = (unmapf(u.x) + unmapf(u.y)) + (unmapf(u.z) + unmapf(u.w));
    #pragma unroll
    for (int off = 32; off > 0; off >>= 1)
        s += __shfl_down(s, off);
    __shared__ float sm[4];
    if ((threadIdx.x & 63) == 0) sm[threadIdx.x >> 6] = s;
    __syncthreads();
    if (threadIdx.x == 0)
        partial[blockIdx.x] = (sm[0] + sm[1]) + (sm[2] + sm[3]);
}

__global__ __launch_bounds__(64) void chamfer_reduce_b(
    const float* __restrict__ partial, float* __restrict__ out)
{
    float s = partial[threadIdx.x];
    #pragma unroll
    for (int off = 32; off > 0; off >>= 1)
        s += __shfl_down(s, off);
    if (threadIdx.x == 0) out[0] = s * (1.0f / (float)BB);
}

extern "C" void kernel_launch(void* const* d_in, const int* in_sizes, int n_in,
                              void* d_out, int out_size, void* d_ws, size_t ws_size,
                              hipStream_t stream) {
    const float* pred   = (const float*)d_in[0];
    const float* gt     = (const float*)d_in[1];
    const float* coords = (const float*)d_in[2];
    unsigned*    wsu    = (unsigned*)d_ws;     // 2*B*N uints = 256 KB
    float*       part   = (float*)((char*)d_ws + (size_t)2 * BB * NN * sizeof(unsigned));
    float*       out    = (float*)d_out;

    ws_init_kernel<<<64, 256, 0, stream>>>(wsu);
    dim3 grid(NBQ * MS, BB);                   // 512 x 4 = 2048 blocks
    chamfer_onepass_kernel<<<grid, TPB, 0, stream>>>(pred, gt, coords, wsu);
    chamfer_reduce_a<<<64, 256, 0, stream>>>(wsu, part);
    chamfer_reduce_b<<<1, 64, 0, stream>>>(part, out);
}